// Round 3
// baseline (490.761 us; speedup 1.0000x reference)
//
#include <hip/hip_runtime.h>

// ConvLatticeModule: out[N,32] = gather(LV, idx)[N,288] @ W[288,32] + bias
// fp32 in/out. R3: (1) pre-pass converts LV fp32->bf16 into d_ws (64 MB,
// L3-resident; halves gather bytes; hot-loop A-load = one dwordx4);
// (2) W fragments staged in LDS (18 KB) instead of 72 regs -> occupancy
// 6 waves/SIMD via __launch_bounds__(256,6); (3) 1536 blocks (6/CU).
//
// MFMA 16x16x32_bf16, one wave = 16 vertices x 32 filters.
//   A layout: A[m=lane&15][k=quad*8+j]  (quad=lane>>4)
//   C/D layout: col(filter)=lane&15, row(vertex)=quad*4+reg   [m89]

typedef __attribute__((ext_vector_type(8))) short short8;
typedef __attribute__((ext_vector_type(4))) float floatx4;

__device__ __forceinline__ unsigned short f2bf(float f) {
    union { float f; unsigned int i; } x;
    x.f = f;
    unsigned int i = x.i;
    i += 0x7fffu + ((i >> 16) & 1u);   // RNE
    return (unsigned short)(i >> 16);
}

#define KNB 9

// ---------- kernel 1: LV fp32 -> bf16 staging ----------
__global__ __launch_bounds__(256) void cvt_lv_kernel(
    const float* __restrict__ lv, unsigned short* __restrict__ lvb, int nvec8)
{
    const int tid = (int)(blockIdx.x * blockDim.x + threadIdx.x);
    const int stride = (int)(gridDim.x * blockDim.x);
    const floatx4* in4 = (const floatx4*)lv;
    short8* out8 = (short8*)lvb;
    for (int i = tid; i < nvec8; i += stride) {
        const floatx4 lo = in4[2 * i];
        const floatx4 hi = in4[2 * i + 1];
        short8 o;
#pragma unroll
        for (int j = 0; j < 4; ++j) {
            o[j]     = (short)f2bf(lo[j]);
            o[j + 4] = (short)f2bf(hi[j]);
        }
        out8[i] = o;
    }
}

// ---------- kernel 2: gather + MFMA ----------
__global__ __launch_bounds__(256, 6) void conv_lattice_kernel(
    const unsigned short* __restrict__ lvb,  // [N][32] bf16 (staged)
    const int* __restrict__ nbr,             // [N][9]
    const float* __restrict__ w,             // [288][32] fp32
    const float* __restrict__ bias,          // [32] fp32
    float* __restrict__ out,                 // [N][32] fp32
    int ntiles)
{
    const int lane = (int)(threadIdx.x & 63u);
    const int m = lane & 15;
    const int quad = lane >> 4;
    const int tid = (int)threadIdx.x;

    // W fragments in LDS, layout [k][t][quad][m][j], j contiguous (16B units):
    // flat i = (((k*2+t)*4+quad)*16 + m)*8 + j
    __shared__ unsigned short wlds[KNB * 2 * 4 * 16 * 8];  // 9216 elems, 18 KB
    for (int i = tid; i < KNB * 2 * 4 * 16 * 8; i += 256) {
        const int j  = i & 7;
        const int mm = (i >> 3) & 15;
        const int qq = (i >> 7) & 3;
        const int tt = (i >> 9) & 1;
        const int kk = i >> 10;
        wlds[i] = f2bf(w[(kk * 32 + qq * 8 + j) * 32 + tt * 16 + mm]);
    }
    __syncthreads();

    const float bias0 = bias[m];
    const float bias1 = bias[m + 16];

    // per-lane base offset (bytes/elems) of its B fragments for given k:
    // elem offset = (((k*2+t)*4+quad)*16 + m)*8
    const int bofs = (quad * 16 + m) * 8;

    const int wave = (int)((blockIdx.x * blockDim.x + threadIdx.x) >> 6);
    const int nw = (int)((gridDim.x * blockDim.x) >> 6);

    for (int t = wave; t < ntiles; t += nw) {
        const int vbase = t << 4;
        const int ibase = (vbase + m) * KNB;

        int idx[KNB];
#pragma unroll
        for (int k = 0; k < KNB; ++k) idx[k] = nbr[ibase + k];

        short8 a[KNB];
#pragma unroll
        for (int k = 0; k < KNB; ++k)
            a[k] = *(const short8*)(lvb + (size_t)idx[k] * 32 + quad * 8);

        floatx4 acc0 = {0.f, 0.f, 0.f, 0.f};
        floatx4 acc1 = {0.f, 0.f, 0.f, 0.f};
#pragma unroll
        for (int k = 0; k < KNB; ++k) {
            const short8 b0 = *(const short8*)&wlds[(k * 2 + 0) * 512 + bofs];
            const short8 b1 = *(const short8*)&wlds[(k * 2 + 1) * 512 + bofs];
            acc0 = __builtin_amdgcn_mfma_f32_16x16x32_bf16(a[k], b0, acc0, 0, 0, 0);
            acc1 = __builtin_amdgcn_mfma_f32_16x16x32_bf16(a[k], b1, acc1, 0, 0, 0);
        }

        const int vrow = vbase + quad * 4;
#pragma unroll
        for (int i = 0; i < 4; ++i) {
            float* o = out + (size_t)(vrow + i) * 32;
            o[m]      = acc0[i] + bias0;
            o[m + 16] = acc1[i] + bias1;
        }
    }
}

// ---------- fallback (ws too small): R2 direct-fp32 kernel ----------
__global__ __launch_bounds__(256, 3) void conv_lattice_fp32_kernel(
    const float* __restrict__ lv, const int* __restrict__ nbr,
    const float* __restrict__ w, const float* __restrict__ bias,
    float* __restrict__ out, int ntiles)
{
    const int lane = (int)(threadIdx.x & 63u);
    const int m = lane & 15;
    const int quad = lane >> 4;
    short8 bfrag[KNB][2];
#pragma unroll
    for (int k = 0; k < KNB; ++k)
#pragma unroll
        for (int t = 0; t < 2; ++t) {
            short8 b;
#pragma unroll
            for (int j = 0; j < 8; ++j)
                b[j] = (short)f2bf(w[(k * 32 + quad * 8 + j) * 32 + t * 16 + m]);
            bfrag[k][t] = b;
        }
    const float bias0 = bias[m];
    const float bias1 = bias[m + 16];
    const int wave = (int)((blockIdx.x * blockDim.x + threadIdx.x) >> 6);
    const int nw = (int)((gridDim.x * blockDim.x) >> 6);
    for (int t = wave; t < ntiles; t += nw) {
        const int vbase = t << 4;
        floatx4 acc0 = {0.f, 0.f, 0.f, 0.f};
        floatx4 acc1 = {0.f, 0.f, 0.f, 0.f};
        const int ibase = (vbase + m) * KNB;
#pragma unroll
        for (int k = 0; k < KNB; ++k) {
            const int nb = nbr[ibase + k];
            const floatx4* rp = (const floatx4*)(lv + (size_t)nb * 32 + quad * 8);
            const floatx4 lo = rp[0];
            const floatx4 hi = rp[1];
            short8 a;
#pragma unroll
            for (int j = 0; j < 4; ++j) {
                a[j]     = (short)f2bf(lo[j]);
                a[j + 4] = (short)f2bf(hi[j]);
            }
            acc0 = __builtin_amdgcn_mfma_f32_16x16x32_bf16(a, bfrag[k][0], acc0, 0, 0, 0);
            acc1 = __builtin_amdgcn_mfma_f32_16x16x32_bf16(a, bfrag[k][1], acc1, 0, 0, 0);
        }
        const int vrow = vbase + quad * 4;
#pragma unroll
        for (int i = 0; i < 4; ++i) {
            float* o = out + (size_t)(vrow + i) * 32;
            o[m]      = acc0[i] + bias0;
            o[m + 16] = acc1[i] + bias1;
        }
    }
}

extern "C" void kernel_launch(void* const* d_in, const int* in_sizes, int n_in,
                              void* d_out, int out_size, void* d_ws, size_t ws_size,
                              hipStream_t stream) {
    const float* lv   = (const float*)d_in[0];
    const int*   nbr  = (const int*)d_in[1];
    const float* w    = (const float*)d_in[2];
    const float* bias = (const float*)d_in[3];
    float*       out  = (float*)d_out;

    const int nelem = in_sizes[0];        // N*32
    const int n = nelem / 32;
    const int ntiles = n / 16;

    const size_t need = (size_t)nelem * 2; // bf16 staging bytes
    if (ws_size >= need) {
        unsigned short* lvb = (unsigned short*)d_ws;
        hipLaunchKernelGGL(cvt_lv_kernel, dim3(2048), dim3(256), 0, stream,
                           lv, lvb, nelem / 8);
        hipLaunchKernelGGL(conv_lattice_kernel, dim3(1536), dim3(256), 0, stream,
                           lvb, nbr, w, bias, out, ntiles);
    } else {
        hipLaunchKernelGGL(conv_lattice_fp32_kernel, dim3(1536), dim3(256), 0, stream,
                           lv, nbr, w, bias, out, ntiles);
    }
}